// Round 1
// baseline (380.480 us; speedup 1.0000x reference)
//
#include <hip/hip_runtime.h>
#include <math.h>

#define DIM  2048
#define NEXP 32
#define DFF  1024
#define NTOK 1024
#define TOPK 4
#define NGRP 4
#define EPG  8
#define SCALE 2.5f

#define BM 64
#define BN 64
#define BK 64
#define MAX_TILES 128
#define MAX_ROWS  7168   // 4096 + 32*63 padding + 1024 shared, rounded up

typedef unsigned int  uint_t;
typedef unsigned short us_t;

typedef __attribute__((ext_vector_type(8))) short bf16x8;
typedef __attribute__((ext_vector_type(4))) float f32x4;

__device__ inline us_t f2b(float f) {
  uint_t u = __float_as_uint(f);
  u += 0x7FFFu + ((u >> 16) & 1u);   // RNE
  return (us_t)(u >> 16);
}

__device__ inline uint4 cvt8(float4 a, float4 b) {
  uint4 r;
  r.x = (uint_t)f2b(a.x) | ((uint_t)f2b(a.y) << 16);
  r.y = (uint_t)f2b(a.z) | ((uint_t)f2b(a.w) << 16);
  r.z = (uint_t)f2b(b.x) | ((uint_t)f2b(b.y) << 16);
  r.w = (uint_t)f2b(b.z) | ((uint_t)f2b(b.w) << 16);
  return r;
}

// ---------------- x -> bf16 ----------------
__global__ __launch_bounds__(256) void xcast_kernel(const float4* __restrict__ x4,
                                                    uint2* __restrict__ xb4) {
  int i = blockIdx.x * 256 + threadIdx.x;
  float4 v = x4[i];
  uint2 o;
  o.x = (uint_t)f2b(v.x) | ((uint_t)f2b(v.y) << 16);
  o.y = (uint_t)f2b(v.z) | ((uint_t)f2b(v.w) << 16);
  xb4[i] = o;
}

// ---------------- router: gates + faithful group/topk select ----------------
__global__ __launch_bounds__(64) void router_kernel(const float* __restrict__ x,
                                                    const float* __restrict__ gw,
                                                    const float* __restrict__ bias,
                                                    int* __restrict__ inds,
                                                    float* __restrict__ wts) {
  int t = blockIdx.x, l = threadIdx.x;
  float xr[32];
#pragma unroll
  for (int i = 0; i < 32; i++) xr[i] = x[t * DIM + i * 64 + l];
  __shared__ float lg[NEXP];
  for (int e = 0; e < NEXP; e++) {
    const float* w = gw + e * DIM;
    float acc = 0.f;
#pragma unroll
    for (int i = 0; i < 32; i++) acc += xr[i] * w[i * 64 + l];
#pragma unroll
    for (int off = 32; off > 0; off >>= 1) acc += __shfl_xor(acc, off);
    if (l == 0) lg[e] = acc;
  }
  __syncthreads();
  if (l != 0) return;

  float s[NEXP], sb[NEXP], mv[NEXP];
#pragma unroll
  for (int e = 0; e < NEXP; e++) {
    float sv = 1.f / (1.f + expf(-lg[e]));
    s[e] = sv; sb[e] = sv + bias[e];
  }
  float gs[NGRP];
#pragma unroll
  for (int g = 0; g < NGRP; g++) {
    float m1 = -1e30f, m2 = -1e30f;
#pragma unroll
    for (int j = 0; j < EPG; j++) {
      float v = sb[g * EPG + j];
      if (v > m1) { m2 = m1; m1 = v; } else if (v > m2) { m2 = v; }
    }
    gs[g] = m1 + m2;
  }
  int g1 = 0;
#pragma unroll
  for (int g = 1; g < NGRP; g++) if (gs[g] > gs[g1]) g1 = g;
  int g2 = -1; float g2v = -1e30f;
#pragma unroll
  for (int g = 0; g < NGRP; g++) {
    if (g == g1) continue;
    if (gs[g] > g2v) { g2v = gs[g]; g2 = g; }
  }
  // faithful mask: only column 0 of each selected group survives
#pragma unroll
  for (int e = 0; e < NEXP; e++) {
    bool keep = (e == g1 * EPG) || (e == g2 * EPG);
    mv[e] = keep ? sb[e] : 0.f;
  }
  // stable top-4 (desc value, ties -> lowest index), weights from UNbiased sigmoid
  uint_t used = 0; float wsum = 0.f;
  int id[TOPK]; float wv[TOPK];
#pragma unroll
  for (int kk = 0; kk < TOPK; kk++) {
    float bv = -1e30f, bs = 0.f; int best = 0;
#pragma unroll
    for (int e = 0; e < NEXP; e++) {
      bool ok = !((used >> e) & 1u) && (mv[e] > bv);
      if (ok) { bv = mv[e]; best = e; bs = s[e]; }
    }
    used |= (1u << best);
    id[kk] = best; wv[kk] = bs; wsum += bs;
  }
  float inv = SCALE / (wsum + 1e-20f);
#pragma unroll
  for (int kk = 0; kk < TOPK; kk++) {
    inds[t * TOPK + kk] = id[kk];
    wts[t * TOPK + kk] = wv[kk] * inv;
  }
}

// ---------------- plan: stable per-expert compaction + tile descriptors ----------------
__global__ __launch_bounds__(256) void plan_kernel(const int* __restrict__ inds,
                                                   const float* __restrict__ wts,
                                                   int* __restrict__ row2tok,
                                                   float* __restrict__ roww,
                                                   int* __restrict__ tileE,
                                                   int* __restrict__ tileR,
                                                   int* __restrict__ nT) {
  __shared__ int scan[256];
  __shared__ int s_off, s_nt;
  int tid = threadIdx.x;
  if (tid == 0) { s_off = 0; s_nt = 0; }
  __syncthreads();
  for (int e = 0; e < NEXP; e++) {
    int off0 = s_off;
    int slot[4]; int cnt = 0;
    int tb = tid * 4;
#pragma unroll
    for (int j = 0; j < 4; j++) {
      int t = tb + j; int sl = -1;
#pragma unroll
      for (int k = 0; k < TOPK; k++) if (inds[t * TOPK + k] == e) sl = k;
      slot[j] = sl; cnt += (sl >= 0) ? 1 : 0;
    }
    scan[tid] = cnt; __syncthreads();
    for (int off = 1; off < 256; off <<= 1) {
      int v = scan[tid];
      int u = (tid >= off) ? scan[tid - off] : 0;
      __syncthreads();
      scan[tid] = v + u;
      __syncthreads();
    }
    int total = scan[255];
    int r = off0 + scan[tid] - cnt;
#pragma unroll
    for (int j = 0; j < 4; j++) {
      if (slot[j] >= 0) {
        int t = tb + j;
        row2tok[r] = t; roww[r] = wts[t * TOPK + slot[j]];
        r++;
      }
    }
    int ntm = (total + BM - 1) / BM;
    int padEnd = off0 + ntm * BM;
    for (int q = off0 + total + tid; q < padEnd; q += 256) { row2tok[q] = 0; roww[q] = 0.f; }
    __syncthreads();
    if (tid == 0) {
      for (int i = 0; i < ntm; i++) { tileE[s_nt + i] = e; tileR[s_nt + i] = off0 + i * BM; }
      s_nt += ntm; s_off = padEnd;
    }
    __syncthreads();
  }
  int off0 = s_off;
  for (int t = tid; t < NTOK; t += 256) { row2tok[off0 + t] = t; roww[off0 + t] = 1.f; }
  if (tid == 0) {
    for (int i = 0; i < NTOK / BM; i++) { tileE[s_nt + i] = NEXP; tileR[s_nt + i] = off0 + i * BM; }
    nT[0] = s_nt + NTOK / BM;
  }
}

// ---------------- gate/up GEMM: H = silu(X Wg^T) * (X Wu^T), bf16 out ----------------
__global__ __launch_bounds__(256) void gateup_kernel(const us_t* __restrict__ xb,
                                                     const float* __restrict__ Wg,
                                                     const float* __restrict__ Wu,
                                                     const float* __restrict__ sWg,
                                                     const float* __restrict__ sWu,
                                                     const int* __restrict__ row2tok,
                                                     const int* __restrict__ tileE,
                                                     const int* __restrict__ tileR,
                                                     const int* __restrict__ nT,
                                                     us_t* __restrict__ H) {
  int tile = blockIdx.x;
  if (tile >= nT[0]) return;
  int e = tileE[tile];
  int row0 = tileR[tile];
  int n0 = blockIdx.y * BN;
  const float* wg = (e < NEXP) ? (Wg + (size_t)e * DFF * DIM) : sWg;
  const float* wu = (e < NEXP) ? (Wu + (size_t)e * DFF * DIM) : sWu;

  __shared__ us_t Xs[BM][BK];
  __shared__ us_t Gs[BN][BK];
  __shared__ us_t Us[BN][BK];

  int tid = threadIdx.x;
  int lane = tid & 63;
  int wid = tid >> 6;
  int wm = (wid >> 1) * 32, wn = (wid & 1) * 32;

  int srow = tid >> 2;
  int c0 = (tid & 3) * 2;
  int scol = (tid & 3) * 16;
  int sw = srow & 7;
  int tok = row2tok[row0 + srow];
  const us_t* xrow = xb + (size_t)tok * DIM;
  const float* grow = wg + (size_t)(n0 + srow) * DIM;
  const float* urow = wu + (size_t)(n0 + srow) * DIM;

  f32x4 accg[2][2] = {};
  f32x4 accu[2][2] = {};

  for (int kt = 0; kt < DIM; kt += BK) {
    {
      const uint4* src = (const uint4*)(xrow + kt + scol);
      uint4 a = src[0], b = src[1];
      uint4* dst = (uint4*)&Xs[srow][0];
      dst[c0 ^ sw] = a; dst[(c0 + 1) ^ sw] = b;
    }
    {
      const float4* s4 = (const float4*)(grow + kt + scol);
      float4 a = s4[0], b = s4[1], c = s4[2], d = s4[3];
      uint4* dst = (uint4*)&Gs[srow][0];
      dst[c0 ^ sw] = cvt8(a, b); dst[(c0 + 1) ^ sw] = cvt8(c, d);
    }
    {
      const float4* s4 = (const float4*)(urow + kt + scol);
      float4 a = s4[0], b = s4[1], c = s4[2], d = s4[3];
      uint4* dst = (uint4*)&Us[srow][0];
      dst[c0 ^ sw] = cvt8(a, b); dst[(c0 + 1) ^ sw] = cvt8(c, d);
    }
    __syncthreads();
#pragma unroll
    for (int ks = 0; ks < BK; ks += 32) {
      int cb = (ks >> 3) + (lane >> 4);
      bf16x8 af[2], bg[2], bu[2];
#pragma unroll
      for (int mi = 0; mi < 2; mi++) {
        int r = wm + mi * 16 + (lane & 15);
        af[mi] = *(const bf16x8*)&(((const uint4*)&Xs[r][0])[cb ^ (r & 7)]);
      }
#pragma unroll
      for (int ni = 0; ni < 2; ni++) {
        int r = wn + ni * 16 + (lane & 15);
        bg[ni] = *(const bf16x8*)&(((const uint4*)&Gs[r][0])[cb ^ (r & 7)]);
        bu[ni] = *(const bf16x8*)&(((const uint4*)&Us[r][0])[cb ^ (r & 7)]);
      }
#pragma unroll
      for (int mi = 0; mi < 2; mi++)
#pragma unroll
        for (int ni = 0; ni < 2; ni++) {
          accg[mi][ni] = __builtin_amdgcn_mfma_f32_16x16x32_bf16(af[mi], bg[ni], accg[mi][ni], 0, 0, 0);
          accu[mi][ni] = __builtin_amdgcn_mfma_f32_16x16x32_bf16(af[mi], bu[ni], accu[mi][ni], 0, 0, 0);
        }
    }
    __syncthreads();
  }
#pragma unroll
  for (int mi = 0; mi < 2; mi++) {
#pragma unroll
    for (int j = 0; j < 4; j++) {
      int r = row0 + wm + mi * 16 + (lane >> 4) * 4 + j;
      us_t* hrow = H + (size_t)r * DFF;
#pragma unroll
      for (int ni = 0; ni < 2; ni++) {
        float g = accg[mi][ni][j], u = accu[mi][ni][j];
        float h = (g / (1.f + expf(-g))) * u;
        hrow[n0 + wn + ni * 16 + (lane & 15)] = f2b(h);
      }
    }
  }
}

// ---------------- down GEMM + weighted scatter-add ----------------
__global__ __launch_bounds__(256) void down_kernel(const us_t* __restrict__ H,
                                                   const float* __restrict__ Wd,
                                                   const float* __restrict__ sWd,
                                                   const int* __restrict__ row2tok,
                                                   const float* __restrict__ roww,
                                                   const int* __restrict__ tileE,
                                                   const int* __restrict__ tileR,
                                                   const int* __restrict__ nT,
                                                   float* __restrict__ out) {
  int tile = blockIdx.x;
  if (tile >= nT[0]) return;
  int e = tileE[tile];
  int row0 = tileR[tile];
  int n0 = blockIdx.y * BN;
  const float* wd = (e < NEXP) ? (Wd + (size_t)e * DIM * DFF) : sWd;

  __shared__ us_t Hs[BM][BK];
  __shared__ us_t Ds[BN][BK];

  int tid = threadIdx.x;
  int lane = tid & 63;
  int wid = tid >> 6;
  int wm = (wid >> 1) * 32, wn = (wid & 1) * 32;

  int srow = tid >> 2;
  int c0 = (tid & 3) * 2;
  int scol = (tid & 3) * 16;
  int sw = srow & 7;
  const us_t* hrow = H + (size_t)(row0 + srow) * DFF;
  const float* drow = wd + (size_t)(n0 + srow) * DFF;

  f32x4 acc[2][2] = {};

  for (int kt = 0; kt < DFF; kt += BK) {
    {
      const uint4* src = (const uint4*)(hrow + kt + scol);
      uint4 a = src[0], b = src[1];
      uint4* dst = (uint4*)&Hs[srow][0];
      dst[c0 ^ sw] = a; dst[(c0 + 1) ^ sw] = b;
    }
    {
      const float4* s4 = (const float4*)(drow + kt + scol);
      float4 a = s4[0], b = s4[1], c = s4[2], d = s4[3];
      uint4* dst = (uint4*)&Ds[srow][0];
      dst[c0 ^ sw] = cvt8(a, b); dst[(c0 + 1) ^ sw] = cvt8(c, d);
    }
    __syncthreads();
#pragma unroll
    for (int ks = 0; ks < BK; ks += 32) {
      int cb = (ks >> 3) + (lane >> 4);
      bf16x8 af[2], bw[2];
#pragma unroll
      for (int mi = 0; mi < 2; mi++) {
        int r = wm + mi * 16 + (lane & 15);
        af[mi] = *(const bf16x8*)&(((const uint4*)&Hs[r][0])[cb ^ (r & 7)]);
      }
#pragma unroll
      for (int ni = 0; ni < 2; ni++) {
        int r = wn + ni * 16 + (lane & 15);
        bw[ni] = *(const bf16x8*)&(((const uint4*)&Ds[r][0])[cb ^ (r & 7)]);
      }
#pragma unroll
      for (int mi = 0; mi < 2; mi++)
#pragma unroll
        for (int ni = 0; ni < 2; ni++)
          acc[mi][ni] = __builtin_amdgcn_mfma_f32_16x16x32_bf16(af[mi], bw[ni], acc[mi][ni], 0, 0, 0);
    }
    __syncthreads();
  }
#pragma unroll
  for (int mi = 0; mi < 2; mi++) {
#pragma unroll
    for (int j = 0; j < 4; j++) {
      int r = row0 + wm + mi * 16 + (lane >> 4) * 4 + j;
      float wgt = roww[r];
      int tok = row2tok[r];
      float* orow = out + (size_t)tok * DIM;
#pragma unroll
      for (int ni = 0; ni < 2; ni++) {
        atomicAdd(orow + n0 + wn + ni * 16 + (lane & 15), acc[mi][ni][j] * wgt);
      }
    }
  }
}

extern "C" void kernel_launch(void* const* d_in, const int* in_sizes, int n_in,
                              void* d_out, int out_size, void* d_ws, size_t ws_size,
                              hipStream_t stream) {
  const float* x    = (const float*)d_in[0];
  const float* gw   = (const float*)d_in[1];
  const float* bias = (const float*)d_in[2];
  const float* Wg   = (const float*)d_in[3];
  const float* Wu   = (const float*)d_in[4];
  const float* Wd   = (const float*)d_in[5];
  const float* sWg  = (const float*)d_in[6];
  const float* sWu  = (const float*)d_in[7];
  const float* sWd  = (const float*)d_in[8];
  float* out = (float*)d_out;

  char* p = (char*)d_ws;
  us_t* xb = (us_t*)p;            p += (size_t)NTOK * DIM * 2;
  us_t* H  = (us_t*)p;            p += (size_t)MAX_ROWS * DFF * 2;
  int* inds = (int*)p;            p += NTOK * TOPK * 4;
  float* wts = (float*)p;         p += NTOK * TOPK * 4;
  int* row2tok = (int*)p;         p += MAX_ROWS * 4;
  float* roww = (float*)p;        p += MAX_ROWS * 4;
  int* tileE = (int*)p;           p += MAX_TILES * 4;
  int* tileR = (int*)p;           p += MAX_TILES * 4;
  int* nT = (int*)p;              p += 4;

  hipMemsetAsync(d_out, 0, (size_t)NTOK * DIM * 4, stream);
  hipLaunchKernelGGL(xcast_kernel, dim3(NTOK * DIM / 1024), dim3(256), 0, stream,
                     (const float4*)x, (uint2*)xb);
  hipLaunchKernelGGL(router_kernel, dim3(NTOK), dim3(64), 0, stream, x, gw, bias, inds, wts);
  hipLaunchKernelGGL(plan_kernel, dim3(1), dim3(256), 0, stream,
                     inds, wts, row2tok, roww, tileE, tileR, nT);
  hipLaunchKernelGGL(gateup_kernel, dim3(MAX_TILES, DFF / BN), dim3(256), 0, stream,
                     xb, Wg, Wu, sWg, sWu, row2tok, tileE, tileR, nT, H);
  hipLaunchKernelGGL(down_kernel, dim3(MAX_TILES, DIM / BN), dim3(256), 0, stream,
                     H, Wd, sWd, row2tok, roww, tileE, tileR, nT, out);
}

// Round 2
// 339.747 us; speedup vs baseline: 1.1199x; 1.1199x over previous
//
#include <hip/hip_runtime.h>
#include <hip/hip_bf16.h>
#include <math.h>

#define DIM  2048
#define NEXP 32
#define DFF  1024
#define NTOK 1024
#define TOPK 4
#define NGRP 4
#define EPG  8
#define SCALE 2.5f

#define BM 64
#define BN 64
#define BK 64
#define MC 4            // M-tiles per block (persistent chunk)
#define NCMAX 64        // max chunks (power of 2 for cheap modulo)
#define MAX_ROWS  7168  // 4096 + 32*63 padding + 1024 shared

typedef unsigned int  uint_t;
typedef unsigned short us_t;

typedef __attribute__((ext_vector_type(8))) short bf16x8;
typedef __attribute__((ext_vector_type(4))) float f32x4;

__device__ inline us_t f2b(float f) {
  __hip_bfloat16 h = __float2bfloat16(f);   // RNE, compiles to v_cvt_*_bf16_f32
  return *reinterpret_cast<const us_t*>(&h);
}

__device__ inline uint4 cvt8(float4 a, float4 b) {
  uint4 r;
  r.x = (uint_t)f2b(a.x) | ((uint_t)f2b(a.y) << 16);
  r.y = (uint_t)f2b(a.z) | ((uint_t)f2b(a.w) << 16);
  r.z = (uint_t)f2b(b.x) | ((uint_t)f2b(b.y) << 16);
  r.w = (uint_t)f2b(b.z) | ((uint_t)f2b(b.w) << 16);
  return r;
}

// ---------------- x -> bf16 ----------------
__global__ __launch_bounds__(256) void xcast_kernel(const float4* __restrict__ x4,
                                                    uint2* __restrict__ xb4) {
  int i = blockIdx.x * 256 + threadIdx.x;
  float4 v = x4[i];
  uint2 o;
  o.x = (uint_t)f2b(v.x) | ((uint_t)f2b(v.y) << 16);
  o.y = (uint_t)f2b(v.z) | ((uint_t)f2b(v.w) << 16);
  xb4[i] = o;
}

// ---------------- router ----------------
__global__ __launch_bounds__(64) void router_kernel(const float* __restrict__ x,
                                                    const float* __restrict__ gw,
                                                    const float* __restrict__ bias,
                                                    int* __restrict__ inds,
                                                    float* __restrict__ wts) {
  int t = blockIdx.x, l = threadIdx.x;
  float xr[32];
#pragma unroll
  for (int i = 0; i < 32; i++) xr[i] = x[t * DIM + i * 64 + l];
  __shared__ float lg[NEXP];
  for (int e = 0; e < NEXP; e++) {
    const float* w = gw + e * DIM;
    float acc = 0.f;
#pragma unroll
    for (int i = 0; i < 32; i++) acc += xr[i] * w[i * 64 + l];
#pragma unroll
    for (int off = 32; off > 0; off >>= 1) acc += __shfl_xor(acc, off);
    if (l == 0) lg[e] = acc;
  }
  __syncthreads();
  if (l != 0) return;

  float s[NEXP], sb[NEXP], mv[NEXP];
#pragma unroll
  for (int e = 0; e < NEXP; e++) {
    float sv = 1.f / (1.f + expf(-lg[e]));
    s[e] = sv; sb[e] = sv + bias[e];
  }
  float gs[NGRP];
#pragma unroll
  for (int g = 0; g < NGRP; g++) {
    float m1 = -1e30f, m2 = -1e30f;
#pragma unroll
    for (int j = 0; j < EPG; j++) {
      float v = sb[g * EPG + j];
      if (v > m1) { m2 = m1; m1 = v; } else if (v > m2) { m2 = v; }
    }
    gs[g] = m1 + m2;
  }
  int g1 = 0;
#pragma unroll
  for (int g = 1; g < NGRP; g++) if (gs[g] > gs[g1]) g1 = g;
  int g2 = -1; float g2v = -1e30f;
#pragma unroll
  for (int g = 0; g < NGRP; g++) {
    if (g == g1) continue;
    if (gs[g] > g2v) { g2v = gs[g]; g2 = g; }
  }
#pragma unroll
  for (int e = 0; e < NEXP; e++) {
    bool keep = (e == g1 * EPG) || (e == g2 * EPG);
    mv[e] = keep ? sb[e] : 0.f;
  }
  uint_t used = 0; float wsum = 0.f;
  int id[TOPK]; float wv[TOPK];
#pragma unroll
  for (int kk = 0; kk < TOPK; kk++) {
    float bv = -1e30f, bs = 0.f; int best = 0;
#pragma unroll
    for (int e = 0; e < NEXP; e++) {
      bool ok = !((used >> e) & 1u) && (mv[e] > bv);
      if (ok) { bv = mv[e]; best = e; bs = s[e]; }
    }
    used |= (1u << best);
    id[kk] = best; wv[kk] = bs; wsum += bs;
  }
  float inv = SCALE / (wsum + 1e-20f);
#pragma unroll
  for (int kk = 0; kk < TOPK; kk++) {
    inds[t * TOPK + kk] = id[kk];
    wts[t * TOPK + kk] = wv[kk] * inv;
  }
}

// ---------------- plan: stable compaction + chunk descriptors ----------------
__global__ __launch_bounds__(256) void plan_kernel(const int* __restrict__ inds,
                                                   const float* __restrict__ wts,
                                                   int* __restrict__ row2tok,
                                                   float* __restrict__ roww,
                                                   int* __restrict__ chunkE,
                                                   int* __restrict__ chunkR,
                                                   int* __restrict__ chunkM,
                                                   int* __restrict__ nC) {
  __shared__ int wsum[4];
  __shared__ int s_off, s_nc;
  int tid = threadIdx.x, lane = tid & 63, wv = tid >> 6;
  if (tid == 0) { s_off = 0; s_nc = 0; }
  __syncthreads();
  for (int e = 0; e < NEXP; e++) {
    int off0 = s_off;
    int slot[4]; int cnt = 0;
    int tb = tid * 4;
#pragma unroll
    for (int j = 0; j < 4; j++) {
      int t = tb + j; int sl = -1;
#pragma unroll
      for (int k = 0; k < TOPK; k++) if (inds[t * TOPK + k] == e) sl = k;
      slot[j] = sl; cnt += (sl >= 0) ? 1 : 0;
    }
    int v = cnt;
#pragma unroll
    for (int off = 1; off < 64; off <<= 1) {
      int u = __shfl_up(v, (unsigned)off);
      if (lane >= off) v += u;
    }
    if (lane == 63) wsum[wv] = v;
    __syncthreads();
    int base = 0;
#pragma unroll
    for (int w = 0; w < 4; w++) base += (w < wv) ? wsum[w] : 0;
    int total = wsum[0] + wsum[1] + wsum[2] + wsum[3];
    int r = off0 + base + v - cnt;
#pragma unroll
    for (int j = 0; j < 4; j++) {
      if (slot[j] >= 0) {
        int t = tb + j;
        row2tok[r] = t; roww[r] = wts[t * TOPK + slot[j]];
        r++;
      }
    }
    int ntm = (total + BM - 1) / BM;
    int padEnd = off0 + ntm * BM;
    for (int q = off0 + total + tid; q < padEnd; q += 256) { row2tok[q] = 0; roww[q] = 0.f; }
    __syncthreads();
    if (tid == 0) {
      for (int i = 0; i < ntm; i += MC) {
        chunkE[s_nc] = e; chunkR[s_nc] = off0 + i * BM;
        chunkM[s_nc] = (ntm - i < MC) ? (ntm - i) : MC;
        s_nc++;
      }
      s_off = padEnd;
    }
    __syncthreads();
  }
  int off0 = s_off;
  for (int t = tid; t < NTOK; t += 256) { row2tok[off0 + t] = t; roww[off0 + t] = 1.f; }
  if (tid == 0) {
    for (int i = 0; i < NTOK / BM; i += MC) {
      chunkE[s_nc] = NEXP; chunkR[s_nc] = off0 + i * BM; chunkM[s_nc] = MC; s_nc++;
    }
    nC[0] = s_nc;
  }
}

// ---------------- gate/up GEMM, M-chunked ----------------
__global__ __launch_bounds__(256) void gateup_kernel(const us_t* __restrict__ xb,
                                                     const float* __restrict__ Wg,
                                                     const float* __restrict__ Wu,
                                                     const float* __restrict__ sWg,
                                                     const float* __restrict__ sWu,
                                                     const int* __restrict__ row2tok,
                                                     const int* __restrict__ chunkE,
                                                     const int* __restrict__ chunkR,
                                                     const int* __restrict__ chunkM,
                                                     const int* __restrict__ nC,
                                                     us_t* __restrict__ H) {
  // XCD-chunked remap: consecutive chunks of same (e, n0) share the B panel -> same XCD L2
  int wg = blockIdx.y * gridDim.x + blockIdx.x;            // 0..1023
  int work = (wg & 7) * (NCMAX * (DFF / BN) / 8) + (wg >> 3);
  int c = work & (NCMAX - 1);
  int n0 = (work >> 6) * BN;
  if (c >= nC[0]) return;
  int e = chunkE[c], row0 = chunkR[c], mc = chunkM[c];
  const float* wgp = (e < NEXP) ? (Wg + (size_t)e * DFF * DIM) : sWg;
  const float* wup = (e < NEXP) ? (Wu + (size_t)e * DFF * DIM) : sWu;

  __shared__ us_t Xs[MC][BM][BK];
  __shared__ us_t Gs[BN][BK];
  __shared__ us_t Us[BN][BK];

  int tid = threadIdx.x;
  int lane = tid & 63;
  int wid = tid >> 6;
  int wm = (wid >> 1) * 32, wn = (wid & 1) * 32;

  int srow = tid >> 2;
  int c0 = (tid & 3) * 2;
  int scol = (tid & 3) * 16;
  int sw = srow & 7;

  const us_t* xrow[MC];
#pragma unroll
  for (int m = 0; m < MC; m++) {
    int tok = (m < mc) ? row2tok[row0 + m * BM + srow] : 0;
    xrow[m] = xb + (size_t)tok * DIM;
  }
  const float* grow = wgp + (size_t)(n0 + srow) * DIM;
  const float* urow = wup + (size_t)(n0 + srow) * DIM;

  f32x4 accg[MC][2][2] = {};
  f32x4 accu[MC][2][2] = {};

  for (int kt = 0; kt < DIM; kt += BK) {
#pragma unroll
    for (int m = 0; m < MC; m++) {
      if (m < mc) {
        const uint4* src = (const uint4*)(xrow[m] + kt + scol);
        uint4 a = src[0], b = src[1];
        uint4* dst = (uint4*)&Xs[m][srow][0];
        dst[c0 ^ sw] = a; dst[(c0 + 1) ^ sw] = b;
      }
    }
    {
      const float4* s4 = (const float4*)(grow + kt + scol);
      float4 a = s4[0], b = s4[1], c2 = s4[2], d = s4[3];
      uint4* dst = (uint4*)&Gs[srow][0];
      dst[c0 ^ sw] = cvt8(a, b); dst[(c0 + 1) ^ sw] = cvt8(c2, d);
    }
    {
      const float4* s4 = (const float4*)(urow + kt + scol);
      float4 a = s4[0], b = s4[1], c2 = s4[2], d = s4[3];
      uint4* dst = (uint4*)&Us[srow][0];
      dst[c0 ^ sw] = cvt8(a, b); dst[(c0 + 1) ^ sw] = cvt8(c2, d);
    }
    __syncthreads();
#pragma unroll
    for (int ks = 0; ks < BK; ks += 32) {
      int cb = (ks >> 3) + (lane >> 4);
      bf16x8 bg[2], bu[2];
#pragma unroll
      for (int ni = 0; ni < 2; ni++) {
        int r = wn + ni * 16 + (lane & 15);
        bg[ni] = *(const bf16x8*)&(((const uint4*)&Gs[r][0])[cb ^ (r & 7)]);
        bu[ni] = *(const bf16x8*)&(((const uint4*)&Us[r][0])[cb ^ (r & 7)]);
      }
#pragma unroll
      for (int m = 0; m < MC; m++) {
        if (m < mc) {
          bf16x8 af[2];
#pragma unroll
          for (int mi = 0; mi < 2; mi++) {
            int r = wm + mi * 16 + (lane & 15);
            af[mi] = *(const bf16x8*)&(((const uint4*)&Xs[m][r][0])[cb ^ (r & 7)]);
          }
#pragma unroll
          for (int mi = 0; mi < 2; mi++)
#pragma unroll
            for (int ni = 0; ni < 2; ni++) {
              accg[m][mi][ni] = __builtin_amdgcn_mfma_f32_16x16x32_bf16(af[mi], bg[ni], accg[m][mi][ni], 0, 0, 0);
              accu[m][mi][ni] = __builtin_amdgcn_mfma_f32_16x16x32_bf16(af[mi], bu[ni], accu[m][mi][ni], 0, 0, 0);
            }
        }
      }
    }
    __syncthreads();
  }
#pragma unroll
  for (int m = 0; m < MC; m++) {
    if (m < mc) {
#pragma unroll
      for (int mi = 0; mi < 2; mi++) {
#pragma unroll
        for (int j = 0; j < 4; j++) {
          int r = row0 + m * BM + wm + mi * 16 + (lane >> 4) * 4 + j;
          us_t* hrow = H + (size_t)r * DFF;
#pragma unroll
          for (int ni = 0; ni < 2; ni++) {
            float g = accg[m][mi][ni][j], u = accu[m][mi][ni][j];
            float h = (g / (1.f + expf(-g))) * u;
            hrow[n0 + wn + ni * 16 + (lane & 15)] = f2b(h);
          }
        }
      }
    }
  }
}

// ---------------- down GEMM + weighted scatter-add, M-chunked ----------------
__global__ __launch_bounds__(256) void down_kernel(const us_t* __restrict__ H,
                                                   const float* __restrict__ Wd,
                                                   const float* __restrict__ sWd,
                                                   const int* __restrict__ row2tok,
                                                   const float* __restrict__ roww,
                                                   const int* __restrict__ chunkE,
                                                   const int* __restrict__ chunkR,
                                                   const int* __restrict__ chunkM,
                                                   const int* __restrict__ nC,
                                                   float* __restrict__ out) {
  int wg = blockIdx.y * gridDim.x + blockIdx.x;            // 0..2047
  int work = (wg & 7) * (NCMAX * (DIM / BN) / 8) + (wg >> 3);
  int c = work & (NCMAX - 1);
  int n0 = (work >> 6) * BN;
  if (c >= nC[0]) return;
  int e = chunkE[c], row0 = chunkR[c], mc = chunkM[c];
  const float* wd = (e < NEXP) ? (Wd + (size_t)e * DIM * DFF) : sWd;

  __shared__ us_t Hs[MC][BM][BK];
  __shared__ us_t Ds[BN][BK];

  int tid = threadIdx.x;
  int lane = tid & 63;
  int wid = tid >> 6;
  int wm = (wid >> 1) * 32, wn = (wid & 1) * 32;

  int srow = tid >> 2;
  int c0 = (tid & 3) * 2;
  int scol = (tid & 3) * 16;
  int sw = srow & 7;

  const us_t* hrow[MC];
#pragma unroll
  for (int m = 0; m < MC; m++)
    hrow[m] = H + (size_t)(row0 + m * BM + srow) * DFF;
  const float* drow = wd + (size_t)(n0 + srow) * DFF;

  f32x4 acc[MC][2][2] = {};

  for (int kt = 0; kt < DFF; kt += BK) {
#pragma unroll
    for (int m = 0; m < MC; m++) {
      if (m < mc) {
        const uint4* src = (const uint4*)(hrow[m] + kt + scol);
        uint4 a = src[0], b = src[1];
        uint4* dst = (uint4*)&Hs[m][srow][0];
        dst[c0 ^ sw] = a; dst[(c0 + 1) ^ sw] = b;
      }
    }
    {
      const float4* s4 = (const float4*)(drow + kt + scol);
      float4 a = s4[0], b = s4[1], c2 = s4[2], d = s4[3];
      uint4* dst = (uint4*)&Ds[srow][0];
      dst[c0 ^ sw] = cvt8(a, b); dst[(c0 + 1) ^ sw] = cvt8(c2, d);
    }
    __syncthreads();
#pragma unroll
    for (int ks = 0; ks < BK; ks += 32) {
      int cb = (ks >> 3) + (lane >> 4);
      bf16x8 bw[2];
#pragma unroll
      for (int ni = 0; ni < 2; ni++) {
        int r = wn + ni * 16 + (lane & 15);
        bw[ni] = *(const bf16x8*)&(((const uint4*)&Ds[r][0])[cb ^ (r & 7)]);
      }
#pragma unroll
      for (int m = 0; m < MC; m++) {
        if (m < mc) {
          bf16x8 af[2];
#pragma unroll
          for (int mi = 0; mi < 2; mi++) {
            int r = wm + mi * 16 + (lane & 15);
            af[mi] = *(const bf16x8*)&(((const uint4*)&Hs[m][r][0])[cb ^ (r & 7)]);
          }
#pragma unroll
          for (int mi = 0; mi < 2; mi++)
#pragma unroll
            for (int ni = 0; ni < 2; ni++)
              acc[m][mi][ni] = __builtin_amdgcn_mfma_f32_16x16x32_bf16(af[mi], bw[ni], acc[m][mi][ni], 0, 0, 0);
        }
      }
    }
    __syncthreads();
  }
#pragma unroll
  for (int m = 0; m < MC; m++) {
    if (m < mc) {
#pragma unroll
      for (int mi = 0; mi < 2; mi++) {
#pragma unroll
        for (int j = 0; j < 4; j++) {
          int r = row0 + m * BM + wm + mi * 16 + (lane >> 4) * 4 + j;
          float wgt = roww[r];
          int tok = row2tok[r];
          float* orow = out + (size_t)tok * DIM;
#pragma unroll
          for (int ni = 0; ni < 2; ni++)
            atomicAdd(orow + n0 + wn + ni * 16 + (lane & 15), acc[m][mi][ni][j] * wgt);
        }
      }
    }
  }
}

extern "C" void kernel_launch(void* const* d_in, const int* in_sizes, int n_in,
                              void* d_out, int out_size, void* d_ws, size_t ws_size,
                              hipStream_t stream) {
  const float* x    = (const float*)d_in[0];
  const float* gw   = (const float*)d_in[1];
  const float* bias = (const float*)d_in[2];
  const float* Wg   = (const float*)d_in[3];
  const float* Wu   = (const float*)d_in[4];
  const float* Wd   = (const float*)d_in[5];
  const float* sWg  = (const float*)d_in[6];
  const float* sWu  = (const float*)d_in[7];
  const float* sWd  = (const float*)d_in[8];
  float* out = (float*)d_out;

  char* p = (char*)d_ws;
  us_t* xb = (us_t*)p;            p += (size_t)NTOK * DIM * 2;
  us_t* H  = (us_t*)p;            p += (size_t)MAX_ROWS * DFF * 2;
  int* inds = (int*)p;            p += NTOK * TOPK * 4;
  float* wts = (float*)p;         p += NTOK * TOPK * 4;
  int* row2tok = (int*)p;         p += MAX_ROWS * 4;
  float* roww = (float*)p;        p += MAX_ROWS * 4;
  int* chunkE = (int*)p;          p += NCMAX * 4;
  int* chunkR = (int*)p;          p += NCMAX * 4;
  int* chunkM = (int*)p;          p += NCMAX * 4;
  int* nC = (int*)p;              p += 4;

  hipMemsetAsync(d_out, 0, (size_t)NTOK * DIM * 4, stream);
  hipLaunchKernelGGL(xcast_kernel, dim3(NTOK * DIM / 1024), dim3(256), 0, stream,
                     (const float4*)x, (uint2*)xb);
  hipLaunchKernelGGL(router_kernel, dim3(NTOK), dim3(64), 0, stream, x, gw, bias, inds, wts);
  hipLaunchKernelGGL(plan_kernel, dim3(1), dim3(256), 0, stream,
                     inds, wts, row2tok, roww, chunkE, chunkR, chunkM, nC);
  hipLaunchKernelGGL(gateup_kernel, dim3(NCMAX, DFF / BN), dim3(256), 0, stream,
                     xb, Wg, Wu, sWg, sWu, row2tok, chunkE, chunkR, chunkM, nC, H);
  hipLaunchKernelGGL(down_kernel, dim3(NCMAX, DIM / BN), dim3(256), 0, stream,
                     H, Wd, sWd, row2tok, roww, chunkE, chunkR, chunkM, nC, out);
}

// Round 3
// 258.683 us; speedup vs baseline: 1.4708x; 1.3134x over previous
//
#include <hip/hip_runtime.h>
#include <hip/hip_bf16.h>
#include <math.h>

#define DIM  2048
#define NEXP 32
#define DFF  1024
#define NTOK 1024
#define TOPK 4
#define NGRP 4
#define EPG  8
#define SCALE 2.5f

#define BM 128
#define BN 64
#define BK 64
#define MAX_TILES 80
#define MAX_ROWS  10240   // 80 * 128

typedef unsigned int  uint_t;
typedef unsigned short us_t;

typedef __attribute__((ext_vector_type(8))) short bf16x8;
typedef __attribute__((ext_vector_type(4))) float f32x4;

__device__ inline us_t f2b(float f) {
  __hip_bfloat16 h = __float2bfloat16(f);   // RNE via v_cvt
  return *reinterpret_cast<const us_t*>(&h);
}

__device__ inline uint4 cvt8(float4 a, float4 b) {
  uint4 r;
  r.x = (uint_t)f2b(a.x) | ((uint_t)f2b(a.y) << 16);
  r.y = (uint_t)f2b(a.z) | ((uint_t)f2b(a.w) << 16);
  r.z = (uint_t)f2b(b.x) | ((uint_t)f2b(b.y) << 16);
  r.w = (uint_t)f2b(b.z) | ((uint_t)f2b(b.w) << 16);
  return r;
}

// ---------------- x -> bf16 ----------------
__global__ __launch_bounds__(256) void xcast_kernel(const float4* __restrict__ x4,
                                                    uint2* __restrict__ xb4) {
  int i = blockIdx.x * 256 + threadIdx.x;
  float4 v = x4[i];
  uint2 o;
  o.x = (uint_t)f2b(v.x) | ((uint_t)f2b(v.y) << 16);
  o.y = (uint_t)f2b(v.z) | ((uint_t)f2b(v.w) << 16);
  xb4[i] = o;
}

// ---------------- router ----------------
__global__ __launch_bounds__(64) void router_kernel(const float* __restrict__ x,
                                                    const float* __restrict__ gw,
                                                    const float* __restrict__ bias,
                                                    int* __restrict__ inds,
                                                    float* __restrict__ wts) {
  int t = blockIdx.x, l = threadIdx.x;
  float xr[32];
#pragma unroll
  for (int i = 0; i < 32; i++) xr[i] = x[t * DIM + i * 64 + l];
  __shared__ float lg[NEXP];
  for (int e = 0; e < NEXP; e++) {
    const float* w = gw + e * DIM;
    float acc = 0.f;
#pragma unroll
    for (int i = 0; i < 32; i++) acc += xr[i] * w[i * 64 + l];
#pragma unroll
    for (int off = 32; off > 0; off >>= 1) acc += __shfl_xor(acc, off);
    if (l == 0) lg[e] = acc;
  }
  __syncthreads();
  if (l != 0) return;

  float s[NEXP], sb[NEXP], mv[NEXP];
#pragma unroll
  for (int e = 0; e < NEXP; e++) {
    float sv = 1.f / (1.f + expf(-lg[e]));
    s[e] = sv; sb[e] = sv + bias[e];
  }
  float gs[NGRP];
#pragma unroll
  for (int g = 0; g < NGRP; g++) {
    float m1 = -1e30f, m2 = -1e30f;
#pragma unroll
    for (int j = 0; j < EPG; j++) {
      float v = sb[g * EPG + j];
      if (v > m1) { m2 = m1; m1 = v; } else if (v > m2) { m2 = v; }
    }
    gs[g] = m1 + m2;
  }
  int g1 = 0;
#pragma unroll
  for (int g = 1; g < NGRP; g++) if (gs[g] > gs[g1]) g1 = g;
  int g2 = -1; float g2v = -1e30f;
#pragma unroll
  for (int g = 0; g < NGRP; g++) {
    if (g == g1) continue;
    if (gs[g] > g2v) { g2v = gs[g]; g2 = g; }
  }
#pragma unroll
  for (int e = 0; e < NEXP; e++) {
    bool keep = (e == g1 * EPG) || (e == g2 * EPG);
    mv[e] = keep ? sb[e] : 0.f;
  }
  uint_t used = 0; float wsum = 0.f;
  int id[TOPK]; float wv[TOPK];
#pragma unroll
  for (int kk = 0; kk < TOPK; kk++) {
    float bv = -1e30f, bs = 0.f; int best = 0;
#pragma unroll
    for (int e = 0; e < NEXP; e++) {
      bool ok = !((used >> e) & 1u) && (mv[e] > bv);
      if (ok) { bv = mv[e]; best = e; bs = s[e]; }
    }
    used |= (1u << best);
    id[kk] = best; wv[kk] = bs; wsum += bs;
  }
  float inv = SCALE / (wsum + 1e-20f);
#pragma unroll
  for (int kk = 0; kk < TOPK; kk++) {
    inds[t * TOPK + kk] = id[kk];
    wts[t * TOPK + kk] = wv[kk] * inv;
  }
}

// ---------------- plan: stable compaction + 128-row tile descriptors ----------------
__global__ __launch_bounds__(256) void plan_kernel(const int* __restrict__ inds,
                                                   const float* __restrict__ wts,
                                                   int* __restrict__ row2tok,
                                                   float* __restrict__ roww,
                                                   int* __restrict__ tileE,
                                                   int* __restrict__ tileR,
                                                   int* __restrict__ nT) {
  __shared__ int wsum[4];
  __shared__ int s_off, s_nt;
  int tid = threadIdx.x, lane = tid & 63, wv = tid >> 6;
  if (tid == 0) { s_off = 0; s_nt = 0; }
  __syncthreads();
  for (int e = 0; e < NEXP; e++) {
    int off0 = s_off;
    int slot[4]; int cnt = 0;
    int tb = tid * 4;
#pragma unroll
    for (int j = 0; j < 4; j++) {
      int t = tb + j; int sl = -1;
#pragma unroll
      for (int k = 0; k < TOPK; k++) if (inds[t * TOPK + k] == e) sl = k;
      slot[j] = sl; cnt += (sl >= 0) ? 1 : 0;
    }
    int v = cnt;
#pragma unroll
    for (int off = 1; off < 64; off <<= 1) {
      int u = __shfl_up(v, (unsigned)off);
      if (lane >= off) v += u;
    }
    if (lane == 63) wsum[wv] = v;
    __syncthreads();
    int base = 0;
#pragma unroll
    for (int w = 0; w < 4; w++) base += (w < wv) ? wsum[w] : 0;
    int total = wsum[0] + wsum[1] + wsum[2] + wsum[3];
    int r = off0 + base + v - cnt;
#pragma unroll
    for (int j = 0; j < 4; j++) {
      if (slot[j] >= 0) {
        int t = tb + j;
        row2tok[r] = t; roww[r] = wts[t * TOPK + slot[j]];
        r++;
      }
    }
    int ntm = (total + BM - 1) / BM;
    int padEnd = off0 + ntm * BM;
    for (int q = off0 + total + tid; q < padEnd; q += 256) { row2tok[q] = 0; roww[q] = 0.f; }
    __syncthreads();
    if (tid == 0) {
      for (int i = 0; i < ntm; i++) { tileE[s_nt + i] = e; tileR[s_nt + i] = off0 + i * BM; }
      s_nt += ntm; s_off = padEnd;
    }
    __syncthreads();
  }
  int off0 = s_off;
  for (int t = tid; t < NTOK; t += 256) { row2tok[off0 + t] = t; roww[off0 + t] = 1.f; }
  if (tid == 0) {
    for (int i = 0; i < NTOK / BM; i++) { tileE[s_nt + i] = NEXP; tileR[s_nt + i] = off0 + i * BM; }
    nT[0] = s_nt + NTOK / BM;
  }
}

// ---------------- gate/up GEMM: 128x64 tiles, 8 waves ----------------
__global__ __launch_bounds__(512) void gateup_kernel(const us_t* __restrict__ xb,
                                                     const float* __restrict__ Wg,
                                                     const float* __restrict__ Wu,
                                                     const float* __restrict__ sWg,
                                                     const float* __restrict__ sWu,
                                                     const int* __restrict__ row2tok,
                                                     const int* __restrict__ tileE,
                                                     const int* __restrict__ tileR,
                                                     const int* __restrict__ nT,
                                                     us_t* __restrict__ H) {
  // XCD-chunked remap (bijective: 1280 % 8 == 0): works n0-column-major so
  // blocks sharing a (expert,n0) weight panel run consecutively on one XCD.
  int hw = blockIdx.x;
  int work = (hw & 7) * (MAX_TILES * (DFF / BN) / 8) + (hw >> 3);
  int tile = work % MAX_TILES;
  int n0 = (work / MAX_TILES) * BN;
  if (tile >= nT[0]) return;
  int e = tileE[tile], row0 = tileR[tile];
  const float* wgp = (e < NEXP) ? (Wg + (size_t)e * DFF * DIM) : sWg;
  const float* wup = (e < NEXP) ? (Wu + (size_t)e * DFF * DIM) : sWu;

  __shared__ us_t Xs[BM][BK];
  __shared__ us_t Gs[BN][BK];
  __shared__ us_t Us[BN][BK];

  int tid = threadIdx.x;
  int lane = tid & 63;
  int wid = tid >> 6;
  int wm = (wid >> 1) * 32, wn = (wid & 1) * 32;

  // X staging: 128 rows, each thread 2 16B chunks
  int srow = tid >> 2;
  int c0 = (tid & 3) * 2;
  int scol = (tid & 3) * 16;
  int sw = srow & 7;
  int tok = row2tok[row0 + srow];
  const us_t* xrow = xb + (size_t)tok * DIM;
  // W staging: 64 rows x 8 chunks, one chunk (8 f32 -> 8 bf16) per thread
  int wr = tid >> 3;
  int wc = tid & 7;
  int wsw = wc ^ (wr & 7);
  const float* grow = wgp + (size_t)(n0 + wr) * DIM + wc * 8;
  const float* urow = wup + (size_t)(n0 + wr) * DIM + wc * 8;

  f32x4 accg[2][2] = {};
  f32x4 accu[2][2] = {};

  for (int kt = 0; kt < DIM; kt += BK) {
    {
      const uint4* src = (const uint4*)(xrow + kt + scol);
      uint4 a = src[0], b = src[1];
      uint4* dst = (uint4*)&Xs[srow][0];
      dst[c0 ^ sw] = a; dst[(c0 + 1) ^ sw] = b;
    }
    {
      const float4* s4 = (const float4*)(grow + kt);
      float4 a = s4[0], b = s4[1];
      ((uint4*)&Gs[wr][0])[wsw] = cvt8(a, b);
    }
    {
      const float4* s4 = (const float4*)(urow + kt);
      float4 a = s4[0], b = s4[1];
      ((uint4*)&Us[wr][0])[wsw] = cvt8(a, b);
    }
    __syncthreads();
#pragma unroll
    for (int ks = 0; ks < BK; ks += 32) {
      int cb = (ks >> 3) + (lane >> 4);
      bf16x8 af[2], bg[2], bu[2];
#pragma unroll
      for (int mi = 0; mi < 2; mi++) {
        int r = wm + mi * 16 + (lane & 15);
        af[mi] = *(const bf16x8*)&(((const uint4*)&Xs[r][0])[cb ^ (r & 7)]);
      }
#pragma unroll
      for (int ni = 0; ni < 2; ni++) {
        int r = wn + ni * 16 + (lane & 15);
        bg[ni] = *(const bf16x8*)&(((const uint4*)&Gs[r][0])[cb ^ (r & 7)]);
        bu[ni] = *(const bf16x8*)&(((const uint4*)&Us[r][0])[cb ^ (r & 7)]);
      }
#pragma unroll
      for (int mi = 0; mi < 2; mi++)
#pragma unroll
        for (int ni = 0; ni < 2; ni++) {
          accg[mi][ni] = __builtin_amdgcn_mfma_f32_16x16x32_bf16(af[mi], bg[ni], accg[mi][ni], 0, 0, 0);
          accu[mi][ni] = __builtin_amdgcn_mfma_f32_16x16x32_bf16(af[mi], bu[ni], accu[mi][ni], 0, 0, 0);
        }
    }
    __syncthreads();
  }
#pragma unroll
  for (int mi = 0; mi < 2; mi++) {
#pragma unroll
    for (int j = 0; j < 4; j++) {
      int r = row0 + wm + mi * 16 + (lane >> 4) * 4 + j;
      us_t* hrow = H + (size_t)r * DFF;
#pragma unroll
      for (int ni = 0; ni < 2; ni++) {
        float g = accg[mi][ni][j], u = accu[mi][ni][j];
        float h = (g / (1.f + expf(-g))) * u;
        hrow[n0 + wn + ni * 16 + (lane & 15)] = f2b(h);
      }
    }
  }
}

// ---------------- down GEMM + weighted scatter-add ----------------
__global__ __launch_bounds__(512) void down_kernel(const us_t* __restrict__ H,
                                                   const float* __restrict__ Wd,
                                                   const float* __restrict__ sWd,
                                                   const int* __restrict__ row2tok,
                                                   const float* __restrict__ roww,
                                                   const int* __restrict__ tileE,
                                                   const int* __restrict__ tileR,
                                                   const int* __restrict__ nT,
                                                   float* __restrict__ out) {
  int hw = blockIdx.x;
  int work = (hw & 7) * (MAX_TILES * (DIM / BN) / 8) + (hw >> 3);
  int tile = work % MAX_TILES;
  int n0 = (work / MAX_TILES) * BN;
  if (tile >= nT[0]) return;
  int e = tileE[tile], row0 = tileR[tile];
  const float* wd = (e < NEXP) ? (Wd + (size_t)e * DIM * DFF) : sWd;

  __shared__ us_t Hs[BM][BK];
  __shared__ us_t Ds[BN][BK];

  int tid = threadIdx.x;
  int lane = tid & 63;
  int wid = tid >> 6;
  int wm = (wid >> 1) * 32, wn = (wid & 1) * 32;

  int srow = tid >> 2;
  int c0 = (tid & 3) * 2;
  int scol = (tid & 3) * 16;
  int sw = srow & 7;
  const us_t* hrow = H + (size_t)(row0 + srow) * DFF;
  int wr = tid >> 3;
  int wc = tid & 7;
  int wsw = wc ^ (wr & 7);
  const float* drow = wd + (size_t)(n0 + wr) * DFF + wc * 8;

  f32x4 acc[2][2] = {};

  for (int kt = 0; kt < DFF; kt += BK) {
    {
      const uint4* src = (const uint4*)(hrow + kt + scol);
      uint4 a = src[0], b = src[1];
      uint4* dst = (uint4*)&Hs[srow][0];
      dst[c0 ^ sw] = a; dst[(c0 + 1) ^ sw] = b;
    }
    {
      const float4* s4 = (const float4*)(drow + kt);
      float4 a = s4[0], b = s4[1];
      ((uint4*)&Ds[wr][0])[wsw] = cvt8(a, b);
    }
    __syncthreads();
#pragma unroll
    for (int ks = 0; ks < BK; ks += 32) {
      int cb = (ks >> 3) + (lane >> 4);
      bf16x8 af[2], bw[2];
#pragma unroll
      for (int mi = 0; mi < 2; mi++) {
        int r = wm + mi * 16 + (lane & 15);
        af[mi] = *(const bf16x8*)&(((const uint4*)&Hs[r][0])[cb ^ (r & 7)]);
      }
#pragma unroll
      for (int ni = 0; ni < 2; ni++) {
        int r = wn + ni * 16 + (lane & 15);
        bw[ni] = *(const bf16x8*)&(((const uint4*)&Ds[r][0])[cb ^ (r & 7)]);
      }
#pragma unroll
      for (int mi = 0; mi < 2; mi++)
#pragma unroll
        for (int ni = 0; ni < 2; ni++)
          acc[mi][ni] = __builtin_amdgcn_mfma_f32_16x16x32_bf16(af[mi], bw[ni], acc[mi][ni], 0, 0, 0);
    }
    __syncthreads();
  }
#pragma unroll
  for (int mi = 0; mi < 2; mi++) {
#pragma unroll
    for (int j = 0; j < 4; j++) {
      int r = row0 + wm + mi * 16 + (lane >> 4) * 4 + j;
      float wgt = roww[r];
      int tok = row2tok[r];
      float* orow = out + (size_t)tok * DIM;
#pragma unroll
      for (int ni = 0; ni < 2; ni++)
        atomicAdd(orow + n0 + wn + ni * 16 + (lane & 15), acc[mi][ni][j] * wgt);
    }
  }
}

extern "C" void kernel_launch(void* const* d_in, const int* in_sizes, int n_in,
                              void* d_out, int out_size, void* d_ws, size_t ws_size,
                              hipStream_t stream) {
  const float* x    = (const float*)d_in[0];
  const float* gw   = (const float*)d_in[1];
  const float* bias = (const float*)d_in[2];
  const float* Wg   = (const float*)d_in[3];
  const float* Wu   = (const float*)d_in[4];
  const float* Wd   = (const float*)d_in[5];
  const float* sWg  = (const float*)d_in[6];
  const float* sWu  = (const float*)d_in[7];
  const float* sWd  = (const float*)d_in[8];
  float* out = (float*)d_out;

  char* p = (char*)d_ws;
  us_t* xb = (us_t*)p;            p += (size_t)NTOK * DIM * 2;
  us_t* H  = (us_t*)p;            p += (size_t)MAX_ROWS * DFF * 2;
  int* inds = (int*)p;            p += NTOK * TOPK * 4;
  float* wts = (float*)p;         p += NTOK * TOPK * 4;
  int* row2tok = (int*)p;         p += MAX_ROWS * 4;
  float* roww = (float*)p;        p += MAX_ROWS * 4;
  int* tileE = (int*)p;           p += MAX_TILES * 4;
  int* tileR = (int*)p;           p += MAX_TILES * 4;
  int* nT = (int*)p;              p += 4;

  hipMemsetAsync(d_out, 0, (size_t)NTOK * DIM * 4, stream);
  hipLaunchKernelGGL(xcast_kernel, dim3(NTOK * DIM / 1024), dim3(256), 0, stream,
                     (const float4*)x, (uint2*)xb);
  hipLaunchKernelGGL(router_kernel, dim3(NTOK), dim3(64), 0, stream, x, gw, bias, inds, wts);
  hipLaunchKernelGGL(plan_kernel, dim3(1), dim3(256), 0, stream,
                     inds, wts, row2tok, roww, tileE, tileR, nT);
  hipLaunchKernelGGL(gateup_kernel, dim3(MAX_TILES * (DFF / BN)), dim3(512), 0, stream,
                     xb, Wg, Wu, sWg, sWu, row2tok, tileE, tileR, nT, H);
  hipLaunchKernelGGL(down_kernel, dim3(MAX_TILES * (DIM / BN)), dim3(512), 0, stream,
                     H, Wd, sWd, row2tok, roww, tileE, tileR, nT, out);
}